// Round 1
// 131.761 us; speedup vs baseline: 1.0041x; 1.0041x over previous
//
#include <hip/hip_runtime.h>

#define TDIM 2048

typedef __bf16 bf16_t;
typedef bf16_t bf16x8 __attribute__((ext_vector_type(8)));
typedef float f32x4 __attribute__((ext_vector_type(4)));
typedef unsigned short us8 __attribute__((ext_vector_type(8)));

__device__ __forceinline__ unsigned short f2bf(float x) {
  unsigned u = __builtin_bit_cast(unsigned, x);
  u += 0x7fffu + ((u >> 16) & 1u);            // round-to-nearest-even
  return (unsigned short)(u >> 16);
}

// async global->LDS, 16B per lane; lds base wave-uniform (HW adds lane*16)
__device__ __forceinline__ void gl_lds16(const unsigned short* g, unsigned short* l) {
  __builtin_amdgcn_global_load_lds(
      (const __attribute__((address_space(1))) unsigned int*)g,
      (__attribute__((address_space(3))) unsigned int*)l, 16, 0, 0);
}

// ---------------------------------------------------------------------------
// K0: BN-fold weights -> effWf bf16 in MFMA-fragment order. grid 12 x 256.
// ---------------------------------------------------------------------------
__global__ __launch_bounds__(256) void k_prepw(
    const float* __restrict__ kW, const float* __restrict__ kb,
    const float* __restrict__ kg, const float* __restrict__ kbe,
    const float* __restrict__ kmu, const float* __restrict__ kva,
    const float* __restrict__ qW, const float* __restrict__ qb,
    const float* __restrict__ qg, const float* __restrict__ qbe,
    const float* __restrict__ qmu, const float* __restrict__ qva,
    const float* __restrict__ vW, const float* __restrict__ vb,
    const float* __restrict__ vg, const float* __restrict__ vbe,
    const float* __restrict__ vmu, const float* __restrict__ vva,
    unsigned short* __restrict__ effWf,
    float* __restrict__ effb)
{
  const int idx = blockIdx.x;            // gid*4 + cc
  const int tid = threadIdx.x;
  const int gid = idx >> 2, cc = idx & 3;
  unsigned short* dst = effWf + (size_t)idx * 8192;
#pragma unroll
  for (int pass = 0; pass < 4; ++pass) {
    int f = pass * 256 + tid;
    int ocblk = f >> 7, cblk = (f >> 4) & 7, m = f & 15;
    int G = gid * 128 + ocblk * 16 + m;
    const float* Wp = (G < 64) ? (kW + G * 256)
                     : (G < 128) ? (qW + (G - 64) * 256)
                                 : (vW + (G - 128) * 256);
    float gg = (G < 64) ? kg[G]  : (G < 128) ? qg[G - 64]  : vg[G - 128];
    float vr = (G < 64) ? kva[G] : (G < 128) ? qva[G - 64] : vva[G - 128];
    float inv = gg * rsqrtf(vr + 1e-5f);
    int c = cc * 64 + cblk * 8;
    float4 a = *(const float4*)(Wp + c);
    float4 bq = *(const float4*)(Wp + c + 4);
    ushort4 lo, hi;
    lo.x = f2bf(a.x * inv);  lo.y = f2bf(a.y * inv);
    lo.z = f2bf(a.z * inv);  lo.w = f2bf(a.w * inv);
    hi.x = f2bf(bq.x * inv); hi.y = f2bf(bq.y * inv);
    hi.z = f2bf(bq.z * inv); hi.w = f2bf(bq.w * inv);
    *(ushort4*)(dst + f * 8) = lo;
    *(ushort4*)(dst + f * 8 + 4) = hi;
  }
  if (idx == 0) {
    for (int G = tid; G < 384; G += 256) {
      float gg = (G < 64) ? kg[G]  : (G < 128) ? qg[G - 64]  : vg[G - 128];
      float vr = (G < 64) ? kva[G] : (G < 128) ? qva[G - 64] : vva[G - 128];
      float bb = (G < 64) ? kb[G]  : (G < 128) ? qb[G - 64]  : vb[G - 128];
      float mm = (G < 64) ? kmu[G] : (G < 128) ? qmu[G - 64] : vmu[G - 128];
      float be = (G < 64) ? kbe[G] : (G < 128) ? qbe[G - 64] : vbe[G - 128];
      float inv = gg * rsqrtf(vr + 1e-5f);
      effb[G] = (bb - mm) * inv + be;
    }
  }
}

// ---------------------------------------------------------------------------
// K1: FUSED QKV GEMM. One wg = all 384 oc x 64 t. x read+transposed ONCE.
// W frags loaded directly from L2 (196KB effWf, L2-resident) with 1-iter
// register prefetch -> no global_load_lds in the loop -> barriers only wait
// lgkmcnt; x/W loads stay in flight across them.
// grid (32 tb, 8 b) = 256 wgs, block 512 (8 waves, 48 oc each).
// ---------------------------------------------------------------------------
__global__ __launch_bounds__(512, 2) void k_qkv(
    const unsigned short* __restrict__ effWf,
    const float* __restrict__ effb,
    const float* __restrict__ x,
    unsigned short* __restrict__ vv,
    unsigned short* __restrict__ kTs,
    unsigned short* __restrict__ qTs)
{
  const int tb = blockIdx.x, b = blockIdx.y;
  const int tid = threadIdx.x;
  const int lane = tid & 63, wv = tid >> 6;
  const int m = lane & 15, quad = lane >> 4;
  const int t0 = tb * 64;

  __shared__ unsigned short Xs[64 * 72];   // 64t x 64c, XOR-swizzled (72 pitch)
  __shared__ float effbs[384];

  if (tid < 384) effbs[tid] = effb[tid];

  const float* xb = x + (size_t)b * 256 * TDIM + t0 + lane;
  float xr[8];

  auto loadX = [&](int cc) {
#pragma unroll
    for (int p = 0; p < 2; ++p)
#pragma unroll
      for (int j = 0; j < 4; ++j) {
        int c = cc * 64 + p * 32 + wv * 4 + j;
        xr[p * 4 + j] = xb[(size_t)c * TDIM];
      }
  };
  auto loadW = [&](bf16x8 (&dst)[2][3], int cc) {
#pragma unroll
    for (int kk = 0; kk < 2; ++kk) {
      int cb = kk * 4 + quad;
#pragma unroll
      for (int mt = 0; mt < 3; ++mt) {
        int T = wv * 3 + mt;                 // global 16-oc tile, 0..23
        int gid = T >> 3, ocb = T & 7;
        dst[kk][mt] = *(const bf16x8*)&effWf[
            ((size_t)((gid * 4 + cc) * 1024) + ocb * 128 + cb * 16 + m) * 8];
      }
    }
  };

  const f32x4 fz = {0.f, 0.f, 0.f, 0.f};
  f32x4 acc[3][4];
#pragma unroll
  for (int i = 0; i < 3; ++i)
#pragma unroll
    for (int j = 0; j < 4; ++j) acc[i][j] = fz;

  bf16x8 afn[2][3];
  loadW(afn, 0);
  loadX(0);
#pragma unroll
  for (int cc = 0; cc < 4; ++cc) {
    __syncthreads();                 // Xs WAR (prev frag reads done)
#pragma unroll
    for (int p = 0; p < 2; ++p) {
      int cb4 = p * 32 + wv * 4;
      int swz = (((cb4 >> 3) ^ (lane >> 3)) << 3) | (cb4 & 7);
      ushort4 s4;
      s4.x = f2bf(xr[p * 4 + 0]); s4.y = f2bf(xr[p * 4 + 1]);
      s4.z = f2bf(xr[p * 4 + 2]); s4.w = f2bf(xr[p * 4 + 3]);
      *(ushort4*)&Xs[lane * 72 + swz] = s4;
    }
    if (cc < 3) loadX(cc + 1);
    bf16x8 afc[2][3];
#pragma unroll
    for (int kk = 0; kk < 2; ++kk)
#pragma unroll
      for (int mt = 0; mt < 3; ++mt) afc[kk][mt] = afn[kk][mt];
    if (cc < 3) loadW(afn, cc + 1);
    __syncthreads();                 // Xs visible
#pragma unroll
    for (int kk = 0; kk < 2; ++kk) {
      int cb = kk * 4 + quad;
      bf16x8 bfv[4];
#pragma unroll
      for (int nt = 0; nt < 4; ++nt) {
        int t = nt * 16 + m;
        bfv[nt] = *(const bf16x8*)&Xs[t * 72 + ((cb ^ (t >> 3)) << 3)];
      }
#pragma unroll
      for (int mt = 0; mt < 3; ++mt)
#pragma unroll
        for (int nt = 0; nt < 4; ++nt)
          acc[mt][nt] = __builtin_amdgcn_mfma_f32_16x16x32_bf16(
              afc[kk][mt], bfv[nt], acc[mt][nt], 0, 0, 0);
    }
  }

  // epilogue. D layout: row (oc) = quad*4+r, col (t) = m
#pragma unroll
  for (int mt = 0; mt < 3; ++mt) {
    int T = wv * 3 + mt;
    int ocg = T * 16 + quad * 4;             // global oc of r=0
#pragma unroll
    for (int nt = 0; nt < 4; ++nt) {
      int t = t0 + nt * 16 + m;
      float ys[4];
#pragma unroll
      for (int r = 0; r < 4; ++r)
        ys[r] = fmaxf(acc[mt][nt][r] + effbs[ocg + r], 0.f);
      if (T < 8) {
        ushort4 s4;
        s4.x = f2bf(ys[0]); s4.y = f2bf(ys[1]);
        s4.z = f2bf(ys[2]); s4.w = f2bf(ys[3]);
        if (T < 4) {
          int ocl = ocg;                     // 0..63 (K)
          int col = (((ocl >> 3) ^ (t & 7)) << 3) | (ocl & 7);
          *(ushort4*)(kTs + ((size_t)(b * TDIM + t)) * 64 + col) = s4;
        } else {
          int oq = ocg - 64;                 // 0..63 (Q)
          int col = (((oq >> 3) ^ (t & 7)) << 3) | (oq & 7);
          *(ushort4*)(qTs + ((size_t)(b * TDIM + t)) * 64 + col) = s4;
        }
      } else {
        int c = ocg - 128;                   // V channel
#pragma unroll
        for (int r = 0; r < 4; ++r)
          vv[(size_t)(b * 256 + c + r) * TDIM + t] = f2bf(ys[r]);
      }
    }
  }
}

// ---------------------------------------------------------------------------
// K2: batch-0 row denominators (the reference's [0]-broadcast bug).
// grid 128 (16 rows each), block 512 (8 waves split the 17 s-tiles).
// ---------------------------------------------------------------------------
__global__ __launch_bounds__(512, 1) void k_denom(
    const unsigned short* __restrict__ kTs,
    const unsigned short* __restrict__ qTs,
    float* __restrict__ denom0)
{
  const int t0d = blockIdx.x * 16;
  const int tid = threadIdx.x;
  const int lane = tid & 63, w = tid >> 6;
  const int m = lane & 15, quad = lane >> 4;

  __shared__ unsigned short S[18432];     // Qs 16x64 | Ks 272x64
  unsigned short* Qs = S;
  unsigned short* Ks = S + 1024;
  __shared__ float pmaxs[8][16];
  __shared__ float psums[8][16];

  {
    const unsigned short* qg = qTs + (size_t)t0d * 64;
    const unsigned short* kg = kTs + ((long)t0d - 256) * 64;  // finite garbage, masked
#pragma unroll
    for (int it = 0; it < 5; ++it) {
      int j = it * 512 + tid;
      if (j < 2304) {
        const unsigned short* g = (j < 128) ? (qg + j * 8) : (kg + (size_t)(j - 128) * 8);
        gl_lds16(g, &S[(it * 512 + w * 64) * 8]);
      }
    }
  }
  __syncthreads();

  const int jn = (w == 0) ? 3 : 2;
  f32x4 sc[3];
  {
    int t = m;
    bf16x8 qf0 = *(const bf16x8*)&Qs[t * 64 + ((quad ^ (t & 7)) << 3)];
    bf16x8 qf1 = *(const bf16x8*)&Qs[t * 64 + (((4 + quad) ^ (t & 7)) << 3)];
    const f32x4 fz = {0.f, 0.f, 0.f, 0.f};
#pragma unroll
    for (int jj = 0; jj < 3; ++jj) {
      if (jj < jn) {
        int j = w + jj * 8;
        int sr = 16 * j + m;
        f32x4 a = fz;
        bf16x8 kf0 = *(const bf16x8*)&Ks[sr * 64 + ((quad ^ (sr & 7)) << 3)];
        a = __builtin_amdgcn_mfma_f32_16x16x32_bf16(qf0, kf0, a, 0, 0, 0);
        bf16x8 kf1 = *(const bf16x8*)&Ks[sr * 64 + (((4 + quad) ^ (sr & 7)) << 3)];
        a = __builtin_amdgcn_mfma_f32_16x16x32_bf16(qf1, kf1, a, 0, 0, 0);
        sc[jj] = a;
      }
    }
  }

  float mx[4] = {0.f, 0.f, 0.f, 0.f};
#pragma unroll
  for (int jj = 0; jj < 3; ++jj)
    if (jj < jn) {
      int j = w + jj * 8;
#pragma unroll
      for (int r = 0; r < 4; ++r) {
        float v = sc[jj][r] * 0.125f;
        sc[jj][r] = v;
        int tg = t0d + quad * 4 + r;
        int sg = t0d - 256 + 16 * j + m;
        if (sg >= 0 && sg <= tg && tg - sg < 256) mx[r] = fmaxf(mx[r], v);
      }
    }
#pragma unroll
  for (int d = 1; d < 16; d <<= 1)
#pragma unroll
    for (int r = 0; r < 4; ++r) mx[r] = fmaxf(mx[r], __shfl_xor(mx[r], d, 64));
  if (m == 0)
#pragma unroll
    for (int r = 0; r < 4; ++r) pmaxs[w][quad * 4 + r] = mx[r];
  __syncthreads();

  float mxf[4];
#pragma unroll
  for (int r = 0; r < 4; ++r) {
    float v = pmaxs[0][quad * 4 + r];
#pragma unroll
    for (int ww = 1; ww < 8; ++ww) v = fmaxf(v, pmaxs[ww][quad * 4 + r]);
    mxf[r] = v;
  }
  float sm[4] = {0.f, 0.f, 0.f, 0.f};
#pragma unroll
  for (int jj = 0; jj < 3; ++jj)
    if (jj < jn) {
      int j = w + jj * 8;
#pragma unroll
      for (int r = 0; r < 4; ++r) {
        int tg = t0d + quad * 4 + r;
        int sg = t0d - 256 + 16 * j + m;
        if (sg >= 0 && sg <= tg && tg - sg < 256) sm[r] += __expf(sc[jj][r] - mxf[r]);
      }
    }
#pragma unroll
  for (int d = 1; d < 16; d <<= 1)
#pragma unroll
    for (int r = 0; r < 4; ++r) sm[r] += __shfl_xor(sm[r], d, 64);
  if (m == 0)
#pragma unroll
    for (int r = 0; r < 4; ++r) psums[w][quad * 4 + r] = sm[r];
  __syncthreads();

  if (tid < 16) {
    float s = 0.f;
#pragma unroll
    for (int ww = 0; ww < 8; ++ww) s += psums[ww][tid];
    denom0[t0d + tid] = s;
  }
}

// ---------------------------------------------------------------------------
// K3: banded attention + residual, 32-t workgroups for 2 wg/CU overlap.
// grid (64 tb-swizzled, 8 b) = 512 wgs, block 256 (4 waves).
// Score phase: wave w -> rt = w&1, s-tile stride-2 split (jb = w>>1).
// PV: wave w owns a 64-c strip. LDS 40KB (Q 32x64 + K 288x64; Ps overlaps).
// ---------------------------------------------------------------------------
__global__ __launch_bounds__(256, 2) void k_attn(
    const float* __restrict__ x,
    const unsigned short* __restrict__ vv,
    const unsigned short* __restrict__ kTs,
    const unsigned short* __restrict__ qTs,
    const float* __restrict__ denom0,
    float* __restrict__ out)
{
  const int bx = blockIdx.x, b = blockIdx.y;
  const int tb = (bx >> 3) + 8 * (bx & 7);   // XCD-aware: adjacent tb same XCD
  const int tid = threadIdx.x;
  const int lane = tid & 63, w = tid >> 6;
  const int m = lane & 15, quad = lane >> 4;
  const int t0 = tb * 32;

  // staging: Qs 32x64 (2048 us) + Ks 288x64 (18432 us) = 40KB
  // phase 2: Ps 32 x 296 (9472 us) overlaps SM base
  __shared__ unsigned short SM[20480];
  __shared__ float pmaxs[4][16];
  unsigned short* Qs = SM;
  unsigned short* Ks = SM + 2048;
  unsigned short* Ps = SM;

  {
    const unsigned short* qg = qTs + ((size_t)(b * TDIM + t0)) * 64;
    const unsigned short* kg = kTs + ((long)(b * TDIM + t0) - 256) * 64;  // finite garbage, masked
#pragma unroll
    for (int it = 0; it < 10; ++it) {
      int j = it * 256 + tid;                 // 16B-unit index, 2560 total
      const unsigned short* g = (j < 256) ? (qg + (size_t)j * 8)
                                          : (kg + (size_t)(j - 256) * 8);
      gl_lds16(g, &SM[(it * 256 + w * 64) * 8]);
    }
  }
  const int rt = w & 1, jb = w >> 1;
  const int jn = jb ? 8 : 9;
  float dval[4];
#pragma unroll
  for (int r = 0; r < 4; ++r) dval[r] = denom0[t0 + rt * 16 + quad * 4 + r];
  __syncthreads();                       // B1: staging drained

  f32x4 sc[9];
  {
    int t = rt * 16 + m;
    bf16x8 qf0 = *(const bf16x8*)&Qs[t * 64 + ((quad ^ (t & 7)) << 3)];
    bf16x8 qf1 = *(const bf16x8*)&Qs[t * 64 + (((4 + quad) ^ (t & 7)) << 3)];
    const f32x4 fz = {0.f, 0.f, 0.f, 0.f};
#pragma unroll
    for (int jj = 0; jj < 9; ++jj) {
      if (jj < jn) {
        int js = rt + jb + 2 * jj;          // s-tile in band, rt..rt+16
        int sr = 16 * js + m;
        f32x4 a = fz;
        bf16x8 kf0 = *(const bf16x8*)&Ks[sr * 64 + ((quad ^ (sr & 7)) << 3)];
        a = __builtin_amdgcn_mfma_f32_16x16x32_bf16(qf0, kf0, a, 0, 0, 0);
        bf16x8 kf1 = *(const bf16x8*)&Ks[sr * 64 + (((4 + quad) ^ (sr & 7)) << 3)];
        a = __builtin_amdgcn_mfma_f32_16x16x32_bf16(qf1, kf1, a, 0, 0, 0);
        sc[jj] = a;
      }
    }
  }

  float mx[4] = {0.f, 0.f, 0.f, 0.f};
#pragma unroll
  for (int jj = 0; jj < 9; ++jj)
    if (jj < jn) {
      int js = rt + jb + 2 * jj;
#pragma unroll
      for (int r = 0; r < 4; ++r) {
        float v = sc[jj][r] * 0.125f;
        sc[jj][r] = v;
        int tg = t0 + rt * 16 + quad * 4 + r;
        int sg = t0 - 256 + 16 * js + m;
        if (sg >= 0 && sg <= tg && tg - sg < 256) mx[r] = fmaxf(mx[r], v);
      }
    }
#pragma unroll
  for (int d = 1; d < 16; d <<= 1)
#pragma unroll
    for (int r = 0; r < 4; ++r) mx[r] = fmaxf(mx[r], __shfl_xor(mx[r], d, 64));
  if (m == 0)
#pragma unroll
    for (int r = 0; r < 4; ++r) pmaxs[w][quad * 4 + r] = mx[r];

  __syncthreads();                       // B2: frag reads done + pmax visible

  float mxf[4], rden[4];
#pragma unroll
  for (int r = 0; r < 4; ++r) {
    mxf[r] = fmaxf(pmaxs[rt][quad * 4 + r], pmaxs[rt + 2][quad * 4 + r]);
    rden[r] = 1.f / (dval[r] + 1e-30f);
  }
#pragma unroll
  for (int jj = 0; jj < 9; ++jj)
    if (jj < jn) {
      int js = rt + jb + 2 * jj;
#pragma unroll
      for (int r = 0; r < 4; ++r) {
        int tg = t0 + rt * 16 + quad * 4 + r;
        int sg = t0 - 256 + 16 * js + m;
        bool ib = (sg >= 0 && sg <= tg && tg - sg < 256);
        sc[jj][r] = ib ? __expf(sc[jj][r] - mxf[r]) * rden[r] : 0.f;
      }
    }

  // zero the uncovered 16-col strip per rt (rt=0: cols 272..288; rt=1: 0..16)
  if (jb == 0) {
    int row = rt * 16 + (lane >> 2);
    int col = (rt ? 0 : 272) + (lane & 3) * 4;
    ushort4 z; z.x = 0; z.y = 0; z.z = 0; z.w = 0;
    *(ushort4*)&Ps[row * 296 + col] = z;
  }
  // scatter normalized P (rows rt*16+quad*4+r, cols 16*js+m)
#pragma unroll
  for (int jj = 0; jj < 9; ++jj)
    if (jj < jn) {
      int js = rt + jb + 2 * jj;
      int col = 16 * js + m;
#pragma unroll
      for (int r = 0; r < 4; ++r)
        Ps[(rt * 16 + quad * 4 + r) * 296 + col] = f2bf(sc[jj][r]);
    }

  // V chunk-0 prefetch (4 c-tiles) issued before the barrier
  const int cbase = w * 64;
  const us8 z8 = {0, 0, 0, 0, 0, 0, 0, 0};
  const unsigned short* vrow[4];
  us8 vreg[4];
#pragma unroll
  for (int ct = 0; ct < 4; ++ct) {
    vrow[ct] = vv + (size_t)(b * 256 + cbase + ct * 16 + m) * TDIM;
    vreg[ct] = z8;
  }
  if (t0 >= 256) {
#pragma unroll
    for (int ct = 0; ct < 4; ++ct)
      vreg[ct] = *(const us8*)(vrow[ct] + t0 - 256 + quad * 8);
  }

  __syncthreads();                       // B3: P visible

  // x-residual prefetch (overlaps PV)
  float4 xv[2][4];
#pragma unroll
  for (int mt = 0; mt < 2; ++mt)
#pragma unroll
    for (int ct = 0; ct < 4; ++ct) {
      int c = cbase + ct * 16 + m;
      int t = t0 + mt * 16 + quad * 4;
      xv[mt][ct] = *(const float4*)(x + (size_t)(b * 256 + c) * TDIM + t);
    }

  // ---- PV: 9 V chunks of 32 s; both row-tiles use all 9 (zeros elsewhere) ----
  const f32x4 fz = {0.f, 0.f, 0.f, 0.f};
  f32x4 acc[2][4];
#pragma unroll
  for (int i = 0; i < 2; ++i)
#pragma unroll
    for (int j = 0; j < 4; ++j) acc[i][j] = fz;
#pragma unroll
  for (int chunk = 0; chunk < 9; ++chunk) {
    us8 vn[4];
#pragma unroll
    for (int ct = 0; ct < 4; ++ct) vn[ct] = z8;
    if (chunk < 8) {
      int sbase = t0 - 256 + (chunk + 1) * 32;
      if (sbase >= 0) {
#pragma unroll
        for (int ct = 0; ct < 4; ++ct)
          vn[ct] = *(const us8*)(vrow[ct] + sbase + quad * 8);
      }
    }
#pragma unroll
    for (int mt = 0; mt < 2; ++mt) {
      bf16x8 af = *(const bf16x8*)&Ps[(mt * 16 + m) * 296 + chunk * 32 + quad * 8];
#pragma unroll
      for (int ct = 0; ct < 4; ++ct)
        acc[mt][ct] = __builtin_amdgcn_mfma_f32_16x16x32_bf16(
            af, __builtin_bit_cast(bf16x8, vreg[ct]), acc[mt][ct], 0, 0, 0);
    }
#pragma unroll
    for (int ct = 0; ct < 4; ++ct) vreg[ct] = vn[ct];
  }

  // epilogue: out = x + O^T.  D: col (c) = m, row (t) = quad*4+r
#pragma unroll
  for (int mt = 0; mt < 2; ++mt)
#pragma unroll
    for (int ct = 0; ct < 4; ++ct) {
      int c = cbase + ct * 16 + m;
      int t = t0 + mt * 16 + quad * 4;
      size_t off = (size_t)(b * 256 + c) * TDIM + t;
      float4 o;
      o.x = xv[mt][ct].x + acc[mt][ct][0];
      o.y = xv[mt][ct].y + acc[mt][ct][1];
      o.z = xv[mt][ct].z + acc[mt][ct][2];
      o.w = xv[mt][ct].w + acc[mt][ct][3];
      *(float4*)(out + off) = o;
    }
}

// ---------------------------------------------------------------------------
extern "C" void kernel_launch(void* const* d_in, const int* in_sizes, int n_in,
                              void* d_out, int out_size, void* d_ws, size_t ws_size,
                              hipStream_t stream) {
  const float* x   = (const float*)d_in[0];
  const float* kW  = (const float*)d_in[1];
  const float* kb  = (const float*)d_in[2];
  const float* kg  = (const float*)d_in[3];
  const float* kbe = (const float*)d_in[4];
  const float* kmu = (const float*)d_in[5];
  const float* kva = (const float*)d_in[6];
  const float* qW  = (const float*)d_in[7];
  const float* qb  = (const float*)d_in[8];
  const float* qg  = (const float*)d_in[9];
  const float* qbe = (const float*)d_in[10];
  const float* qmu = (const float*)d_in[11];
  const float* qva = (const float*)d_in[12];
  const float* vW  = (const float*)d_in[13];
  const float* vb  = (const float*)d_in[14];
  const float* vg  = (const float*)d_in[15];
  const float* vbe = (const float*)d_in[16];
  const float* vmu = (const float*)d_in[17];
  const float* vva = (const float*)d_in[18];

  unsigned short* vv  = (unsigned short*)d_ws;                  // 8 MB
  unsigned short* kTs = vv + (size_t)8 * 256 * TDIM;            // 2 MB
  unsigned short* qTs = kTs + (size_t)8 * TDIM * 64;            // 2 MB
  float* denom0 = (float*)(qTs + (size_t)8 * TDIM * 64);        // 8 KB
  unsigned short* effWf = (unsigned short*)(denom0 + 2048);     // 192 KB
  float* effb = (float*)(effWf + 12 * 8192);                    // 1.5 KB
  float* outp = (float*)d_out;

  k_prepw<<<dim3(12), 256, 0, stream>>>(
      kW, kb, kg, kbe, kmu, kva,
      qW, qb, qg, qbe, qmu, qva,
      vW, vb, vg, vbe, vmu, vva, effWf, effb);
  k_qkv<<<dim3(32, 8), 512, 0, stream>>>(effWf, effb, x, vv, kTs, qTs);
  k_denom<<<dim3(128), 512, 0, stream>>>(kTs, qTs, denom0);
  k_attn<<<dim3(64, 8), 256, 0, stream>>>(x, vv, kTs, qTs, denom0, outp);
}